// Round 1
// baseline (2672.986 us; speedup 1.0000x reference)
//
#include <hip/hip_runtime.h>
#include <hip/hip_bf16.h>

using bf16 = __hip_bfloat16;
typedef __attribute__((ext_vector_type(8))) short short8;   // 8 bf16 = 4 VGPRs
typedef __attribute__((ext_vector_type(4))) float f32x4;    // MFMA C/D frag

#define MFMA_BF16(A,B,C) __builtin_amdgcn_mfma_f32_16x16x32_bf16((A),(B),(C),0,0,0)

// async global->LDS, 16B per lane. LDS dest = wave-uniform base + lane*16.
static __device__ __forceinline__ void gload16(const void* g, void* l) {
  __builtin_amdgcn_global_load_lds(
      (const __attribute__((address_space(1))) void*)g,
      (__attribute__((address_space(3))) void*)l, 16, 0, 0);
}

// ---------------------------------------------------------------------------
// Generic bf16 GEMM: C[M,N] = A[M,K] @ B[N,K]^T + bias1 + bias2
// m97 structure: 128x128 tile, BK=32, 4 waves (2x2), 4x4 16x16x32 frags/wave.
// EPI 0: fp32 out (ld = Nreal).  EPI 1: tanh(x*BN_SCALE) -> bf16 out.
// ---------------------------------------------------------------------------
template<int EPI>
__global__ __launch_bounds__(256)
void gemm_bt(const bf16* __restrict__ A, const bf16* __restrict__ B,
             const float* __restrict__ bias1, const float* __restrict__ bias2,
             float* __restrict__ Cf, bf16* __restrict__ Cb,
             int M, int N, int K, int Nreal)
{
  __shared__ __align__(1024) bf16 As[128*32];
  __shared__ __align__(1024) bf16 Bs[128*32];
  const int tid  = threadIdx.x;
  const int wave = tid >> 6, lane = tid & 63;
  const int wr = wave >> 1, wc = wave & 1;
  const int row0 = blockIdx.y * 128;
  const int col0 = blockIdx.x * 128;

  f32x4 acc[4][4];
  #pragma unroll
  for (int m = 0; m < 4; ++m)
    #pragma unroll
    for (int n = 0; n < 4; ++n) { f32x4 z = {0.f,0.f,0.f,0.f}; acc[m][n] = z; }

  const int r_sub = lane >> 2;   // 0..15 (row within 16-row stage group)
  const int kc    = lane & 3;    // 16B chunk within 64B row

  for (int k0 = 0; k0 < K; k0 += 32) {
    __syncthreads();   // protect LDS from previous iteration's readers
    #pragma unroll
    for (int j = 0; j < 2; ++j) {
      const int rb = wave*32 + j*16;   // wave-uniform 16-row group
      gload16(A + (size_t)(row0 + rb + r_sub)*K + k0 + kc*8,
              (void*)((char*)As + (size_t)rb*64));
      gload16(B + (size_t)(col0 + rb + r_sub)*K + k0 + kc*8,
              (void*)((char*)Bs + (size_t)rb*64));
    }
    __syncthreads();   // drains vmcnt -> staged data visible

    short8 af[4], bfv[4];
    #pragma unroll
    for (int m = 0; m < 4; ++m)
      af[m] = *(const short8*)(As + (wr*64 + m*16 + (lane&15))*32 + (lane>>4)*8);
    #pragma unroll
    for (int n = 0; n < 4; ++n)
      bfv[n] = *(const short8*)(Bs + (wc*64 + n*16 + (lane&15))*32 + (lane>>4)*8);
    #pragma unroll
    for (int m = 0; m < 4; ++m)
      #pragma unroll
      for (int n = 0; n < 4; ++n)
        acc[m][n] = MFMA_BF16(af[m], bfv[n], acc[m][n]);
  }

  const float BN_SCALE = 0.9999950000374997f;  // 1/sqrt(1+1e-5)
  #pragma unroll
  for (int m = 0; m < 4; ++m) {
    const int rg0 = row0 + wr*64 + m*16 + ((lane>>4)<<2);
    #pragma unroll
    for (int n = 0; n < 4; ++n) {
      const int cg = col0 + wc*64 + n*16 + (lane&15);
      if (cg < Nreal) {
        float bb = 0.f;
        if (bias1) bb += bias1[cg];
        if (bias2) bb += bias2[cg];
        #pragma unroll
        for (int j = 0; j < 4; ++j) {
          float v = acc[m][n][j] + bb;
          if (EPI == 1) {
            v = tanhf(v * BN_SCALE);
            Cb[(size_t)(rg0+j)*Nreal + cg] = __float2bfloat16(v);
          } else {
            Cf[(size_t)(rg0+j)*Nreal + cg] = v;
          }
        }
      }
    }
  }
}

// ---------------------------------------------------------------------------
// One pipelined LSTM super-step s: blocks 0..31 -> layer0 t=s,
// blocks 32..63 -> layer1 t=s-1.  Each block owns 32 h-cols (=> 128 gate
// cols across the 4 i/f/g/o chunks); wave w handles chunk w.
// gates = [gin] + A1@B1^T [+ A2@B2^T] + [bias1+bias2]; then LSTM cell.
// ---------------------------------------------------------------------------
__global__ __launch_bounds__(256)
void k_lstm_step(int s, const bf16* __restrict__ hinit,
                 const bf16* __restrict__ Whh0, const bf16* __restrict__ Wih1,
                 const bf16* __restrict__ Whh1, const float* __restrict__ g0_all,
                 const float* __restrict__ bih1, const float* __restrict__ bhh1,
                 bf16* __restrict__ h0_all, bf16* __restrict__ h1_all,
                 float* __restrict__ c01, float* __restrict__ tail)
{
  const int layer = blockIdx.x >> 5;
  const int blk   = blockIdx.x & 31;
  const int t = s - layer;
  if (t < 0 || t >= 64) return;

  const bf16 *A1, *B1, *A2 = nullptr, *B2 = nullptr;
  const float *gin = nullptr, *bi1 = nullptr, *bi2 = nullptr;
  float* c = c01 + layer*32768;
  bf16* hout;
  if (layer == 0) {
    A1 = (t == 0) ? hinit : h0_all + (size_t)(t-1)*32768;
    B1 = Whh0;
    gin = g0_all + (size_t)t*131072;
    hout = h0_all + (size_t)t*32768;
  } else {
    A1 = h0_all + (size_t)t*32768;
    B1 = Wih1;
    A2 = (t == 0) ? hinit + 32768 : h1_all + (size_t)(t-1)*32768;
    B2 = Whh1;
    bi1 = bih1; bi2 = bhh1;
    hout = h1_all + (size_t)t*32768;
  }

  const int tid = threadIdx.x;
  const int wave = tid >> 6, lane = tid & 63;
  const int colbase = wave*1024 + blk*32;   // gate-col base for this wave
  const int arow = lane & 15;
  const int koff = (lane >> 4) * 8;

  f32x4 acc[2][2];
  #pragma unroll
  for (int m = 0; m < 2; ++m)
    #pragma unroll
    for (int n = 0; n < 2; ++n) { f32x4 z = {0.f,0.f,0.f,0.f}; acc[m][n] = z; }

  for (int pass = 0; pass < 2; ++pass) {
    const bf16* Ap = pass ? A2 : A1;
    const bf16* Bp = pass ? B2 : B1;
    if (!Ap) break;
    #pragma unroll 2
    for (int k = 0; k < 1024; k += 32) {
      short8 a0 = *(const short8*)(Ap + (size_t)arow*1024 + k + koff);
      short8 a1 = *(const short8*)(Ap + (size_t)(arow+16)*1024 + k + koff);
      #pragma unroll
      for (int n = 0; n < 2; ++n) {
        short8 b = *(const short8*)(Bp + (size_t)(colbase + n*16 + arow)*1024 + k + koff);
        acc[0][n] = MFMA_BF16(a0, b, acc[0][n]);
        acc[1][n] = MFMA_BF16(a1, b, acc[1][n]);
      }
    }
  }

  __shared__ float glds[4][32][32];
  #pragma unroll
  for (int m = 0; m < 2; ++m)
    #pragma unroll
    for (int n = 0; n < 2; ++n)
      #pragma unroll
      for (int j = 0; j < 4; ++j)
        glds[wave][m*16 + (lane>>4)*4 + j][n*16 + (lane&15)] = acc[m][n][j];
  __syncthreads();

  float *hf = nullptr, *cf = nullptr;
  if (t == 63) { hf = tail + layer*32768; cf = tail + 65536 + layer*32768; }

  #pragma unroll
  for (int it = 0; it < 4; ++it) {
    int lin = it*256 + tid;          // 0..1023
    int r = lin >> 5, hc = lin & 31;
    int col = blk*32 + hc;           // h col 0..1023
    float iv = glds[0][r][hc];
    float fv = glds[1][r][hc];
    float gv = glds[2][r][hc];
    float ov = glds[3][r][hc];
    if (gin) {
      const float* gr = gin + (size_t)r*4096;
      iv += gr[col]; fv += gr[1024+col]; gv += gr[2048+col]; ov += gr[3072+col];
    }
    if (bi1) {
      iv += bi1[col]      + bi2[col];
      fv += bi1[1024+col] + bi2[1024+col];
      gv += bi1[2048+col] + bi2[2048+col];
      ov += bi1[3072+col] + bi2[3072+col];
    }
    float co = c[(size_t)r*1024 + col];
    iv = 1.f/(1.f+expf(-iv));
    fv = 1.f/(1.f+expf(-fv));
    gv = tanhf(gv);
    ov = 1.f/(1.f+expf(-ov));
    float cn = fv*co + iv*gv;
    float hn = ov*tanhf(cn);
    c[(size_t)r*1024 + col] = cn;
    hout[(size_t)r*1024 + col] = __float2bfloat16(hn);
    if (hf) { hf[(size_t)r*1024 + col] = hn; cf[(size_t)r*1024 + col] = cn; }
  }
}

// ---------------------------------------------------------------------------
// small helpers
// ---------------------------------------------------------------------------
__global__ void k_cvt(const float* __restrict__ s, bf16* __restrict__ d, long n) {
  long i = (long)blockIdx.x*blockDim.x + threadIdx.x;
  if (i < n) d[i] = __float2bfloat16(s[i]);
}

__global__ void k_cvt_pad(const float* __restrict__ s, bf16* __restrict__ d,
                          long n, long nrows_real, int rowlen) {
  long i = (long)blockIdx.x*blockDim.x + threadIdx.x;
  if (i < n) {
    long r = i / rowlen;
    d[i] = (r < nrows_real) ? __float2bfloat16(s[i]) : __float2bfloat16(0.f);
  }
}

__global__ void k_init(const float* __restrict__ hx, const float* __restrict__ cx,
                       bf16* __restrict__ hinit, float* __restrict__ c01) {
  int i = blockIdx.x*blockDim.x + threadIdx.x;
  if (i < 65536) { hinit[i] = __float2bfloat16(hx[i]); c01[i] = cx[i]; }
}

__global__ void k_embed(const int* __restrict__ ids, const float* __restrict__ emb_w,
                        bf16* __restrict__ out) {
  const int row = blockIdx.x;               // t*32+b, 0..2047
  const int tok = ids[row];
  const float4 v = ((const float4*)(emb_w + (size_t)tok*512))[threadIdx.x];
  bf16* d = out + (size_t)row*512 + threadIdx.x*4;
  d[0] = __float2bfloat16(v.x); d[1] = __float2bfloat16(v.y);
  d[2] = __float2bfloat16(v.z); d[3] = __float2bfloat16(v.w);
}

// ---------------------------------------------------------------------------
extern "C" void kernel_launch(void* const* d_in, const int* in_sizes, int n_in,
                              void* d_out, int out_size, void* d_ws, size_t ws_size,
                              hipStream_t stream) {
  const int*   ids  = (const int*)d_in[0];
  const float* hx   = (const float*)d_in[1];
  const float* cx   = (const float*)d_in[2];
  const float* embw = (const float*)d_in[3];
  const float* Wih0 = (const float*)d_in[4];
  const float* Whh0 = (const float*)d_in[5];
  const float* bih0 = (const float*)d_in[6];
  const float* bhh0 = (const float*)d_in[7];
  const float* Wih1 = (const float*)d_in[8];
  const float* Whh1 = (const float*)d_in[9];
  const float* bih1 = (const float*)d_in[10];
  const float* bhh1 = (const float*)d_in[11];
  const float* Wp   = (const float*)d_in[12];
  const float* bp   = (const float*)d_in[13];
  const float* Wd   = (const float*)d_in[14];
  const float* bd   = (const float*)d_in[15];
  float* out = (float*)d_out;

  char* w = (char*)d_ws;
  bf16* Wih0b = (bf16*)w; w += 4096l*512*2;
  bf16* Whh0b = (bf16*)w; w += 4096l*1024*2;
  bf16* Wih1b = (bf16*)w; w += 4096l*1024*2;
  bf16* Whh1b = (bf16*)w; w += 4096l*1024*2;
  bf16* Wpb   = (bf16*)w; w += 512l*1024*2;
  bf16* Wdb   = (bf16*)w; w += 50048l*512*2;
  bf16* embb  = (bf16*)w; w += 2048l*512*2;
  float* g0   = (float*)w; w += 2048l*4096*4;
  bf16* h0a   = (bf16*)w; w += 2048l*1024*2;
  bf16* h1a   = (bf16*)w; w += 2048l*1024*2;
  bf16* hinit = (bf16*)w; w += 2l*32*1024*2;
  float* c01  = (float*)w; w += 2l*32*1024*4;
  bf16* pb    = (bf16*)w; w += 2048l*512*2;

  // weight casts (re-done every call: no persistent state allowed)
  k_cvt<<<(4096l*512 + 255)/256, 256, 0, stream>>>(Wih0, Wih0b, 4096l*512);
  k_cvt<<<(4096l*1024 + 255)/256, 256, 0, stream>>>(Whh0, Whh0b, 4096l*1024);
  k_cvt<<<(4096l*1024 + 255)/256, 256, 0, stream>>>(Wih1, Wih1b, 4096l*1024);
  k_cvt<<<(4096l*1024 + 255)/256, 256, 0, stream>>>(Whh1, Whh1b, 4096l*1024);
  k_cvt<<<(512l*1024 + 255)/256, 256, 0, stream>>>(Wp, Wpb, 512l*1024);
  k_cvt_pad<<<(50048l*512 + 255)/256, 256, 0, stream>>>(Wd, Wdb, 50048l*512, 50000, 512);
  k_init<<<256, 256, 0, stream>>>(hx, cx, hinit, c01);
  k_embed<<<2048, 128, 0, stream>>>(ids, embw, embb);

  // layer-0 input-side GEMM for ALL timesteps (off the sequential path)
  gemm_bt<0><<<dim3(32, 16), 256, 0, stream>>>(
      embb, Wih0b, bih0, bhh0, g0, nullptr, 2048, 4096, 512, 4096);

  // pipelined recurrence: 65 super-steps
  float* tail = out + 102400000l;
  for (int s = 0; s < 65; ++s)
    k_lstm_step<<<64, 256, 0, stream>>>(s, hinit, Whh0b, Wih1b, Whh1b, g0,
                                        bih1, bhh1, h0a, h1a, c01, tail);

  // predictor: Linear + BN(eval) + tanh -> bf16
  gemm_bt<1><<<dim3(4, 16), 256, 0, stream>>>(
      h1a, Wpb, bp, nullptr, nullptr, pb, 2048, 512, 1024, 512);

  // decoder: [2048,512] @ [50048,512]^T (padded), guarded store to 50000
  gemm_bt<0><<<dim3(391, 16), 256, 0, stream>>>(
      pb, Wdb, bd, nullptr, out, nullptr, 2048, 50048, 512, 50000);
}

// Round 2
// 1505.748 us; speedup vs baseline: 1.7752x; 1.7752x over previous
//
#include <hip/hip_runtime.h>
#include <hip/hip_bf16.h>

using bf16 = __hip_bfloat16;
typedef __attribute__((ext_vector_type(8))) short short8;   // 8 bf16 = 4 VGPRs
typedef __attribute__((ext_vector_type(4))) float f32x4;    // MFMA C/D frag

#define MFMA_BF16(A,B,C) __builtin_amdgcn_mfma_f32_16x16x32_bf16((A),(B),(C),0,0,0)

// async global->LDS, 16B per lane. LDS dest = wave-uniform base + lane*16.
static __device__ __forceinline__ void gload16(const void* g, void* l) {
  __builtin_amdgcn_global_load_lds(
      (const __attribute__((address_space(1))) void*)g,
      (__attribute__((address_space(3))) void*)l, 16, 0, 0);
}

// ---------------------------------------------------------------------------
// Generic bf16 GEMM: C[M,N] = A[M,K] @ B[N,K]^T + bias1 + bias2
// m97 structure: 128x128 tile, BK=32, 4 waves (2x2), 4x4 16x16x32 frags/wave.
// EPI 0: fp32 out (ld = Nreal).  EPI 1: tanh(x*BN_SCALE) -> bf16 out.
// ---------------------------------------------------------------------------
template<int EPI>
__global__ __launch_bounds__(256)
void gemm_bt(const bf16* __restrict__ A, const bf16* __restrict__ B,
             const float* __restrict__ bias1, const float* __restrict__ bias2,
             float* __restrict__ Cf, bf16* __restrict__ Cb,
             int M, int N, int K, int Nreal)
{
  __shared__ __align__(1024) bf16 As[128*32];
  __shared__ __align__(1024) bf16 Bs[128*32];
  const int tid  = threadIdx.x;
  const int wave = tid >> 6, lane = tid & 63;
  const int wr = wave >> 1, wc = wave & 1;
  const int row0 = blockIdx.y * 128;
  const int col0 = blockIdx.x * 128;

  f32x4 acc[4][4];
  #pragma unroll
  for (int m = 0; m < 4; ++m)
    #pragma unroll
    for (int n = 0; n < 4; ++n) { f32x4 z = {0.f,0.f,0.f,0.f}; acc[m][n] = z; }

  const int r_sub = lane >> 2;   // 0..15 (row within 16-row stage group)
  const int kc    = lane & 3;    // 16B chunk within 64B row

  for (int k0 = 0; k0 < K; k0 += 32) {
    __syncthreads();   // protect LDS from previous iteration's readers
    #pragma unroll
    for (int j = 0; j < 2; ++j) {
      const int rb = wave*32 + j*16;   // wave-uniform 16-row group
      gload16(A + (size_t)(row0 + rb + r_sub)*K + k0 + kc*8,
              (void*)((char*)As + (size_t)rb*64));
      gload16(B + (size_t)(col0 + rb + r_sub)*K + k0 + kc*8,
              (void*)((char*)Bs + (size_t)rb*64));
    }
    __syncthreads();   // drains vmcnt -> staged data visible

    short8 af[4], bfv[4];
    #pragma unroll
    for (int m = 0; m < 4; ++m)
      af[m] = *(const short8*)(As + (wr*64 + m*16 + (lane&15))*32 + (lane>>4)*8);
    #pragma unroll
    for (int n = 0; n < 4; ++n)
      bfv[n] = *(const short8*)(Bs + (wc*64 + n*16 + (lane&15))*32 + (lane>>4)*8);
    #pragma unroll
    for (int m = 0; m < 4; ++m)
      #pragma unroll
      for (int n = 0; n < 4; ++n)
        acc[m][n] = MFMA_BF16(af[m], bfv[n], acc[m][n]);
  }

  const float BN_SCALE = 0.9999950000374997f;  // 1/sqrt(1+1e-5)
  #pragma unroll
  for (int m = 0; m < 4; ++m) {
    const int rg0 = row0 + wr*64 + m*16 + ((lane>>4)<<2);
    #pragma unroll
    for (int n = 0; n < 4; ++n) {
      const int cg = col0 + wc*64 + n*16 + (lane&15);
      if (cg < Nreal) {
        float bb = 0.f;
        if (bias1) bb += bias1[cg];
        if (bias2) bb += bias2[cg];
        #pragma unroll
        for (int j = 0; j < 4; ++j) {
          float v = acc[m][n][j] + bb;
          if (EPI == 1) {
            v = tanhf(v * BN_SCALE);
            Cb[(size_t)(rg0+j)*Nreal + cg] = __float2bfloat16(v);
          } else {
            Cf[(size_t)(rg0+j)*Nreal + cg] = v;
          }
        }
      }
    }
  }
}

// ---------------------------------------------------------------------------
// Persistent LSTM recurrence kernel.
// Grid = 256 blocks x 256 threads (>= capacity for co-residency: 16KB LDS,
// modest VGPR -> >=2 blocks/CU capacity; grid == CU count).
// Block b owns h-cols [4b, 4b+4) of BOTH layers. Weights pre-packed in
// MFMA-fragment order (k_pack) so every weight read is a coalesced 16B/lane
// stream that stays pinned in the block's XCD L2 across all 65 steps.
// Per super-step s: layer0 computes t=s, layer1 computes t=s-1 (diagonal
// pipeline). Cell state c: ONE register per thread for the whole recurrence.
// Grid barrier: monotonic counter, AGENT-scope release/acquire atomics
// (emits buffer_wbl2/buffer_inv sc1 -> correct across non-coherent XCD L2s).
// ---------------------------------------------------------------------------
__device__ __forceinline__ void gridbar(unsigned* cnt, int s, int tid) {
  __syncthreads();                     // all threads done with this step
  if (tid == 0) {
    __hip_atomic_fetch_add(cnt, 1u, __ATOMIC_RELEASE, __HIP_MEMORY_SCOPE_AGENT);
    const unsigned target = (unsigned)(s + 1) * 256u;
    while (__hip_atomic_load(cnt, __ATOMIC_ACQUIRE, __HIP_MEMORY_SCOPE_AGENT) < target)
      __builtin_amdgcn_s_sleep(2);
  }
  __syncthreads();                     // fan acquire out to the block
}

__global__ __launch_bounds__(256)
void k_lstm_persist(const bf16* __restrict__ hinit, const float* __restrict__ cx,
                    const bf16* __restrict__ Wpack, const float* __restrict__ g0,
                    const float* __restrict__ bih1, const float* __restrict__ bhh1,
                    bf16* __restrict__ h0_all, bf16* __restrict__ h1_all,
                    float* __restrict__ tail, unsigned* __restrict__ bar)
{
  const int b    = blockIdx.x;
  const int tid  = threadIdx.x;
  const int wave = tid >> 6, lane = tid & 63;

  __shared__ float P[4][2][32][16];    // [wave][layer][batch][gatecol j]

  // --- gate/cell phase thread mapping: one LSTM cell per thread ---
  const int layer = tid >> 7;          // 0 or 1
  const int cell  = tid & 127;
  const int r     = cell >> 2;         // batch 0..31
  const int hc    = cell & 3;          // h-col within block
  const int col   = b*4 + hc;          // global h-col
  float creg = cx[(size_t)layer*32768 + (size_t)r*1024 + col];
  float bsum[4];
  #pragma unroll
  for (int g = 0; g < 4; ++g)
    bsum[g] = (layer == 1) ? (bih1[g*1024 + col] + bhh1[g*1024 + col]) : 0.f;

  // --- MFMA phase constants ---
  const bf16* wbase = Wpack + (size_t)b * 96 * 64 * 8;  // 96 chunks x 64 lanes x 8 bf16
  const int arow = lane & 15;
  const int koff = (lane >> 4) * 8;

  for (int s = 0; s < 65; ++s) {
    const bf16* hA = (s == 0) ? hinit           : h0_all + (size_t)(s-1)*32768;
    const bf16* hB = (s <= 1) ? (hinit + 32768) : h1_all + (size_t)(s-2)*32768;

    f32x4 z = {0.f,0.f,0.f,0.f};
    f32x4 acc00 = z, acc01 = z, acc10 = z, acc11 = z;  // [layer][m-frag]

    #pragma unroll
    for (int i = 0; i < 8; ++i) {
      const int kb = (wave*8 + i) * 32;                 // this wave's K-quarter
      short8 a0 = *(const short8*)(hA + (size_t)arow*1024      + kb + koff);
      short8 a1 = *(const short8*)(hA + (size_t)(arow+16)*1024 + kb + koff);
      short8 b0 = *(const short8*)(wbase + ((size_t)(     wave*8+i)*64 + lane)*8);
      short8 b1 = *(const short8*)(wbase + ((size_t)(32 + wave*8+i)*64 + lane)*8);
      acc00 = MFMA_BF16(a0, b0, acc00);                 // layer0: Whh0 @ h0[s-1]
      acc01 = MFMA_BF16(a1, b0, acc01);
      acc10 = MFMA_BF16(a0, b1, acc10);                 // layer1: Wih1 @ h0[s-1]
      acc11 = MFMA_BF16(a1, b1, acc11);
      short8 c0 = *(const short8*)(hB + (size_t)arow*1024      + kb + koff);
      short8 c1 = *(const short8*)(hB + (size_t)(arow+16)*1024 + kb + koff);
      short8 b2 = *(const short8*)(wbase + ((size_t)(64 + wave*8+i)*64 + lane)*8);
      acc10 = MFMA_BF16(c0, b2, acc10);                 // layer1 += Whh1 @ h1[s-2]
      acc11 = MFMA_BF16(c1, b2, acc11);
    }

    // write K-quarter partials (previous step's P readers finished at gridbar)
    #pragma unroll
    for (int j = 0; j < 4; ++j) {
      const int pr = (lane >> 4)*4 + j;
      P[wave][0][pr     ][lane & 15] = acc00[j];
      P[wave][0][pr + 16][lane & 15] = acc01[j];
      P[wave][1][pr     ][lane & 15] = acc10[j];
      P[wave][1][pr + 16][lane & 15] = acc11[j];
    }
    __syncthreads();

    // gate + cell phase
    const int t = s - layer;
    if (t >= 0 && t < 64) {
      float v[4];
      #pragma unroll
      for (int g = 0; g < 4; ++g) {
        const int j = g*4 + hc;
        v[g] = P[0][layer][r][j] + P[1][layer][r][j]
             + P[2][layer][r][j] + P[3][layer][r][j] + bsum[g];
      }
      if (layer == 0) {
        const float* gr = g0 + ((size_t)t*32 + r)*4096;
        #pragma unroll
        for (int g = 0; g < 4; ++g) v[g] += gr[g*1024 + col];
      }
      const float iv = 1.f/(1.f + expf(-v[0]));
      const float fv = 1.f/(1.f + expf(-v[1]));
      const float gv = tanhf(v[2]);
      const float ov = 1.f/(1.f + expf(-v[3]));
      creg = fv*creg + iv*gv;
      const float hn = ov*tanhf(creg);
      bf16* hout = (layer ? h1_all : h0_all) + (size_t)t*32768 + (size_t)r*1024 + col;
      *hout = __float2bfloat16(hn);
      if (t == 63) {
        tail[(size_t)layer*32768 + (size_t)r*1024 + col]         = hn;
        tail[65536 + (size_t)layer*32768 + (size_t)r*1024 + col] = creg;
      }
    }
    gridbar(bar, s, tid);
  }
}

// ---------------------------------------------------------------------------
// Pack Whh0 / Wih1 / Whh1 (fp32 [4096,1024] row-major) into per-block
// MFMA-fragment order, cast to bf16. Block b, part p, chunk c, lane l:
//   slot = W_p[(j>>2)*1024 + b*4 + (j&3)][c*32 + (l>>4)*8 .. +7], j=l&15.
// ---------------------------------------------------------------------------
__global__ __launch_bounds__(256)
void k_pack(const float* __restrict__ Whh0, const float* __restrict__ Wih1,
            const float* __restrict__ Whh1, bf16* __restrict__ Wpack)
{
  const int b = blockIdx.x;
  #pragma unroll 4
  for (int it = 0; it < 24; ++it) {
    const int idx = it*256 + threadIdx.x;   // 0..6143
    const int chunkp = idx >> 6;            // 0..95
    const int l = idx & 63;
    const int p = chunkp >> 5, c = chunkp & 31;
    const float* W = (p == 0) ? Whh0 : (p == 1 ? Wih1 : Whh1);
    const int j = l & 15;
    const int row = (j>>2)*1024 + b*4 + (j&3);
    const int k = c*32 + (l>>4)*8;
    const float* src = W + (size_t)row*1024 + k;
    bf16* dst = Wpack + ((size_t)(b*96 + chunkp)*64 + l)*8;
    #pragma unroll
    for (int q = 0; q < 8; ++q) dst[q] = __float2bfloat16(src[q]);
  }
}

// ---------------------------------------------------------------------------
// small helpers
// ---------------------------------------------------------------------------
__global__ void k_cvt(const float* __restrict__ s, bf16* __restrict__ d, long n) {
  long i = (long)blockIdx.x*blockDim.x + threadIdx.x;
  if (i < n) d[i] = __float2bfloat16(s[i]);
}

__global__ void k_cvt_pad(const float* __restrict__ s, bf16* __restrict__ d,
                          long n, long nrows_real, int rowlen) {
  long i = (long)blockIdx.x*blockDim.x + threadIdx.x;
  if (i < n) {
    long r = i / rowlen;
    d[i] = (r < nrows_real) ? __float2bfloat16(s[i]) : __float2bfloat16(0.f);
  }
}

__global__ void k_init(const float* __restrict__ hx, bf16* __restrict__ hinit,
                       unsigned* __restrict__ bar) {
  int i = blockIdx.x*blockDim.x + threadIdx.x;
  if (i == 0) *bar = 0u;
  if (i < 65536) hinit[i] = __float2bfloat16(hx[i]);
}

__global__ void k_embed(const int* __restrict__ ids, const float* __restrict__ emb_w,
                        bf16* __restrict__ out) {
  const int row = blockIdx.x;               // t*32+b, 0..2047
  const int tok = ids[row];
  const float4 v = ((const float4*)(emb_w + (size_t)tok*512))[threadIdx.x];
  bf16* d = out + (size_t)row*512 + threadIdx.x*4;
  d[0] = __float2bfloat16(v.x); d[1] = __float2bfloat16(v.y);
  d[2] = __float2bfloat16(v.z); d[3] = __float2bfloat16(v.w);
}

// ---------------------------------------------------------------------------
extern "C" void kernel_launch(void* const* d_in, const int* in_sizes, int n_in,
                              void* d_out, int out_size, void* d_ws, size_t ws_size,
                              hipStream_t stream) {
  const int*   ids  = (const int*)d_in[0];
  const float* hx   = (const float*)d_in[1];
  const float* cx   = (const float*)d_in[2];
  const float* embw = (const float*)d_in[3];
  const float* Wih0 = (const float*)d_in[4];
  const float* Whh0 = (const float*)d_in[5];
  const float* bih0 = (const float*)d_in[6];
  const float* bhh0 = (const float*)d_in[7];
  const float* Wih1 = (const float*)d_in[8];
  const float* Whh1 = (const float*)d_in[9];
  const float* bih1 = (const float*)d_in[10];
  const float* bhh1 = (const float*)d_in[11];
  const float* Wp   = (const float*)d_in[12];
  const float* bp   = (const float*)d_in[13];
  const float* Wd   = (const float*)d_in[14];
  const float* bd   = (const float*)d_in[15];
  float* out = (float*)d_out;

  char* w = (char*)d_ws;
  bf16* Wih0b = (bf16*)w; w += 4096l*512*2;
  bf16* Wpack = (bf16*)w; w += 256l*96*64*8*2;   // 24 MB packed recurrent weights
  bf16* Wpb   = (bf16*)w; w += 512l*1024*2;
  bf16* Wdb   = (bf16*)w; w += 50048l*512*2;
  bf16* embb  = (bf16*)w; w += 2048l*512*2;
  float* g0   = (float*)w; w += 2048l*4096*4;
  bf16* h0a   = (bf16*)w; w += 2048l*1024*2;
  bf16* h1a   = (bf16*)w; w += 2048l*1024*2;
  bf16* hinit = (bf16*)w; w += 2l*32*1024*2;
  bf16* pb    = (bf16*)w; w += 2048l*512*2;
  unsigned* bar = (unsigned*)w; w += 256;

  // prep (all independent of the recurrence)
  k_cvt<<<(4096l*512 + 255)/256, 256, 0, stream>>>(Wih0, Wih0b, 4096l*512);
  k_cvt<<<(512l*1024 + 255)/256, 256, 0, stream>>>(Wp, Wpb, 512l*1024);
  k_cvt_pad<<<(50048l*512 + 255)/256, 256, 0, stream>>>(Wd, Wdb, 50048l*512, 50000, 512);
  k_init<<<256, 256, 0, stream>>>(hx, hinit, bar);
  k_embed<<<2048, 128, 0, stream>>>(ids, embw, embb);
  k_pack<<<256, 256, 0, stream>>>(Whh0, Wih1, Whh1, Wpack);

  // layer-0 input-side GEMM for ALL timesteps (off the sequential path);
  // folds bih0+bhh0.
  gemm_bt<0><<<dim3(32, 16), 256, 0, stream>>>(
      embb, Wih0b, bih0, bhh0, g0, nullptr, 2048, 4096, 512, 4096);

  // persistent pipelined recurrence: 65 super-steps, one dispatch
  float* tail = out + 102400000l;
  k_lstm_persist<<<256, 256, 0, stream>>>(hinit, cx, Wpack, g0, bih1, bhh1,
                                          h0a, h1a, tail, bar);

  // predictor: Linear + BN(eval) + tanh -> bf16
  gemm_bt<1><<<dim3(4, 16), 256, 0, stream>>>(
      h1a, Wpb, bp, nullptr, nullptr, pb, 2048, 512, 1024, 512);

  // decoder: [2048,512] @ [50048,512]^T (padded), guarded store to 50000
  gemm_bt<0><<<dim3(391, 16), 256, 0, stream>>>(
      pb, Wdb, bd, nullptr, out, nullptr, 2048, 50048, 512, 50000);
}

// Round 4
// 1209.864 us; speedup vs baseline: 2.2093x; 1.2446x over previous
//
#include <hip/hip_runtime.h>
#include <hip/hip_bf16.h>

using bf16 = __hip_bfloat16;
typedef __attribute__((ext_vector_type(8))) short short8;   // 8 bf16 = 4 VGPRs
typedef __attribute__((ext_vector_type(4))) float f32x4;    // MFMA C/D frag

#define MFMA_BF16(A,B,C) __builtin_amdgcn_mfma_f32_16x16x32_bf16((A),(B),(C),0,0,0)

static __device__ __forceinline__ unsigned bf16bits(float f) {
  union { bf16 h; unsigned short u; } cv; cv.h = __float2bfloat16(f); return cv.u;
}

// async global->LDS, 16B per lane. LDS dest = wave-uniform base + lane*16.
static __device__ __forceinline__ void gload16(const void* g, void* l) {
  __builtin_amdgcn_global_load_lds(
      (const __attribute__((address_space(1))) void*)g,
      (__attribute__((address_space(3))) void*)l, 16, 0, 0);
}

// ---------------------------------------------------------------------------
// Generic bf16 GEMM: C[M,N] = A[M,K] @ B[N,K]^T (+bias)
// m97 structure: 128x128 tile, BK=32, 4 waves (2x2), 4x4 16x16x32 frags/wave.
// EPI 0: fp32 out, ld=Nreal.  EPI 1: tanh(x*BN_SCALE) -> bf16.
// EPI 2: g0p write — B is the ROW-PERMUTED Wih0 (n -> orig g*1024+b*4+hc),
//        output scattered to [b][t][r][q] (q=g*4+hc) for coalesced gate reads.
// ---------------------------------------------------------------------------
template<int EPI>
__global__ __launch_bounds__(256)
void gemm_bt(const bf16* __restrict__ A, const bf16* __restrict__ B,
             const float* __restrict__ bias1, const float* __restrict__ bias2,
             float* __restrict__ Cf, bf16* __restrict__ Cb,
             int M, int N, int K, int Nreal)
{
  __shared__ __align__(1024) bf16 As[128*32];
  __shared__ __align__(1024) bf16 Bs[128*32];
  const int tid  = threadIdx.x;
  const int wave = tid >> 6, lane = tid & 63;
  const int wr = wave >> 1, wc = wave & 1;
  const int row0 = blockIdx.y * 128;
  const int col0 = blockIdx.x * 128;

  f32x4 acc[4][4];
  #pragma unroll
  for (int m = 0; m < 4; ++m)
    #pragma unroll
    for (int n = 0; n < 4; ++n) { f32x4 z = {0.f,0.f,0.f,0.f}; acc[m][n] = z; }

  const int r_sub = lane >> 2;   // 0..15 (row within 16-row stage group)
  const int kc    = lane & 3;    // 16B chunk within 64B row

  for (int k0 = 0; k0 < K; k0 += 32) {
    __syncthreads();
    #pragma unroll
    for (int j = 0; j < 2; ++j) {
      const int rb = wave*32 + j*16;
      gload16(A + (size_t)(row0 + rb + r_sub)*K + k0 + kc*8,
              (void*)((char*)As + (size_t)rb*64));
      gload16(B + (size_t)(col0 + rb + r_sub)*K + k0 + kc*8,
              (void*)((char*)Bs + (size_t)rb*64));
    }
    __syncthreads();

    short8 af[4], bfv[4];
    #pragma unroll
    for (int m = 0; m < 4; ++m)
      af[m] = *(const short8*)(As + (wr*64 + m*16 + (lane&15))*32 + (lane>>4)*8);
    #pragma unroll
    for (int n = 0; n < 4; ++n)
      bfv[n] = *(const short8*)(Bs + (wc*64 + n*16 + (lane&15))*32 + (lane>>4)*8);
    #pragma unroll
    for (int m = 0; m < 4; ++m)
      #pragma unroll
      for (int n = 0; n < 4; ++n)
        acc[m][n] = MFMA_BF16(af[m], bfv[n], acc[m][n]);
  }

  const float BN_SCALE = 0.9999950000374997f;  // 1/sqrt(1+1e-5)
  #pragma unroll
  for (int m = 0; m < 4; ++m) {
    const int rg0 = row0 + wr*64 + m*16 + ((lane>>4)<<2);
    #pragma unroll
    for (int n = 0; n < 4; ++n) {
      const int cg = col0 + wc*64 + n*16 + (lane&15);
      if (EPI == 2) {
        const int bq = cg >> 4, q = cg & 15;
        const int orig = (q>>2)*1024 + bq*4 + (q&3);   // permuted -> original col
        const float bb = bias1[orig] + bias2[orig];
        #pragma unroll
        for (int j = 0; j < 4; ++j) {
          const int row = rg0 + j;
          Cf[((size_t)bq*64 + (row>>5))*512 + (size_t)(row&31)*16 + q]
              = acc[m][n][j] + bb;
        }
      } else if (cg < Nreal) {
        float bb = 0.f;
        if (bias1) bb += bias1[cg];
        if (bias2) bb += bias2[cg];
        #pragma unroll
        for (int j = 0; j < 4; ++j) {
          float v = acc[m][n][j] + bb;
          if (EPI == 1) {
            v = tanhf(v * BN_SCALE);
            Cb[(size_t)(rg0+j)*Nreal + cg] = __float2bfloat16(v);
          } else {
            Cf[(size_t)(rg0+j)*Nreal + cg] = v;
          }
        }
      }
    }
  }
}

// ---------------------------------------------------------------------------
// Two-level grid barrier, monotonic counters. grp[g] at bar[16+g*16] (own
// cacheline each), root at bar[0]. Relaxed polling (no per-poll cache ops);
// ONE acquire fence at exit (__builtin_amdgcn_fence, agent scope).
// ---------------------------------------------------------------------------
__device__ __forceinline__ void gridbar2(unsigned* bar, int grpid, int s, int tid) {
  __syncthreads();
  if (tid == 0) {
    unsigned old = __hip_atomic_fetch_add(bar + 16 + grpid*16, 1u,
                       __ATOMIC_ACQ_REL, __HIP_MEMORY_SCOPE_AGENT);
    if (old == (unsigned)(s*32 + 31))          // last block of this group
      __hip_atomic_fetch_add(bar, 1u, __ATOMIC_RELEASE, __HIP_MEMORY_SCOPE_AGENT);
    const unsigned target = (unsigned)(s + 1) * 8u;
    while (__hip_atomic_load(bar, __ATOMIC_RELAXED, __HIP_MEMORY_SCOPE_AGENT) < target)
      __builtin_amdgcn_s_sleep(1);
    __builtin_amdgcn_fence(__ATOMIC_ACQUIRE, "agent");
  }
  __syncthreads();
}

// ---------------------------------------------------------------------------
// Persistent LSTM recurrence. 256 blocks x 256 threads, 1 block/CU,
// __launch_bounds__(256,1) -> up to 512 VGPR/wave. Recurrent weights are
// preloaded into 96 VGPRs per wave ONCE and never touch memory again, so the
// per-step L2 invalidate (acquire) costs nothing. Per step: 32 short8 h-loads
// (LLC) -> 24 MFMAs -> LDS cross-wave reduce -> gate math -> paired bf16x2
// write-through store -> 2-level barrier.
// ---------------------------------------------------------------------------
__global__ __launch_bounds__(256, 1)
void k_lstm_persist(const bf16* __restrict__ hinit, const float* __restrict__ cx,
                    const bf16* __restrict__ Wpack, const float* __restrict__ g0p,
                    const float* __restrict__ bih1, const float* __restrict__ bhh1,
                    bf16* __restrict__ h0_all, bf16* __restrict__ h1_all,
                    float* __restrict__ tail, unsigned* __restrict__ bar)
{
  const int b    = blockIdx.x;
  const int tid  = threadIdx.x;
  const int wave = tid >> 6, lane = tid & 63;
  const int grpid = b >> 5;

  __shared__ float P[4][2][32][20];    // padded: 2-way max on writes

  // gate/cell phase mapping: one LSTM cell per thread
  const int layer = tid >> 7;
  const int cell  = tid & 127;
  const int r     = cell >> 2;
  const int hc    = cell & 3;
  const int col   = b*4 + hc;
  float creg = cx[(size_t)layer*32768 + (size_t)r*1024 + col];
  float bsum[4];
  #pragma unroll
  for (int g = 0; g < 4; ++g)
    bsum[g] = (layer == 1) ? (bih1[g*1024 + col] + bhh1[g*1024 + col]) : 0.f;

  // --- preload all recurrent weights into registers (96 VGPRs/wave) ---
  const bf16* wbase = Wpack + (size_t)b * 96 * 64 * 8;
  short8 w0[8], w1[8], w2[8];
  #pragma unroll
  for (int i = 0; i < 8; ++i) {
    w0[i] = *(const short8*)(wbase + ((size_t)(     wave*8+i)*64 + lane)*8);
    w1[i] = *(const short8*)(wbase + ((size_t)(32 + wave*8+i)*64 + lane)*8);
    w2[i] = *(const short8*)(wbase + ((size_t)(64 + wave*8+i)*64 + lane)*8);
  }

  const int arow = lane & 15;
  const int koff = (lane >> 4) * 8;

  for (int s = 0; s < 65; ++s) {
    const bf16* hA = (s == 0) ? hinit           : h0_all + (size_t)(s-1)*32768;
    const bf16* hB = (s <= 1) ? (hinit + 32768) : h1_all + (size_t)(s-2)*32768;

    // issue ALL h loads up front (32 short8/wave in flight)
    short8 a0[8], a1[8], c0[8], c1[8];
    #pragma unroll
    for (int i = 0; i < 8; ++i) {
      const int kb = (wave*8 + i) * 32;
      a0[i] = *(const short8*)(hA + (size_t)arow*1024      + kb + koff);
      a1[i] = *(const short8*)(hA + (size_t)(arow+16)*1024 + kb + koff);
      c0[i] = *(const short8*)(hB + (size_t)arow*1024      + kb + koff);
      c1[i] = *(const short8*)(hB + (size_t)(arow+16)*1024 + kb + koff);
    }
    // prefetch this step's g0p slice (coalesced, read-once) before the MFMAs
    float gpre[4] = {0.f, 0.f, 0.f, 0.f};
    if (layer == 0 && s < 64) {
      const float* gr = g0p + ((size_t)(b*64 + s)*32 + r)*16;
      #pragma unroll
      for (int g = 0; g < 4; ++g) gpre[g] = gr[g*4 + hc];
    }

    f32x4 z = {0.f,0.f,0.f,0.f};
    f32x4 acc00 = z, acc01 = z, acc10 = z, acc11 = z;
    #pragma unroll
    for (int i = 0; i < 8; ++i) {
      acc00 = MFMA_BF16(a0[i], w0[i], acc00);   // layer0: Whh0 @ h0[s-1]
      acc01 = MFMA_BF16(a1[i], w0[i], acc01);
      acc10 = MFMA_BF16(a0[i], w1[i], acc10);   // layer1: Wih1 @ h0[s-1]
      acc11 = MFMA_BF16(a1[i], w1[i], acc11);
      acc10 = MFMA_BF16(c0[i], w2[i], acc10);   // layer1 += Whh1 @ h1[s-2]
      acc11 = MFMA_BF16(c1[i], w2[i], acc11);
    }

    #pragma unroll
    for (int j = 0; j < 4; ++j) {
      const int pr = (lane >> 4)*4 + j;
      P[wave][0][pr     ][lane & 15] = acc00[j];
      P[wave][0][pr + 16][lane & 15] = acc01[j];
      P[wave][1][pr     ][lane & 15] = acc10[j];
      P[wave][1][pr + 16][lane & 15] = acc11[j];
    }
    __syncthreads();

    const int t = s - layer;
    if (t >= 0 && t < 64) {
      float v[4];
      #pragma unroll
      for (int g = 0; g < 4; ++g) {
        const int j = g*4 + hc;
        v[g] = P[0][layer][r][j] + P[1][layer][r][j]
             + P[2][layer][r][j] + P[3][layer][r][j] + bsum[g] + gpre[g];
      }
      const float iv = 1.f/(1.f + expf(-v[0]));
      const float fv = 1.f/(1.f + expf(-v[1]));
      const float gv = tanhf(v[2]);
      const float ov = 1.f/(1.f + expf(-v[3]));
      creg = fv*creg + iv*gv;
      const float hn = ov*tanhf(creg);
      // pair 2 bf16 -> one 4B write-through agent store
      unsigned hu = bf16bits(hn);
      unsigned up = (unsigned)__shfl_xor((int)hu, 1);
      if ((hc & 1) == 0) {
        bf16* hp = (layer ? h1_all : h0_all) + (size_t)t*32768 + (size_t)r*1024 + col;
        __hip_atomic_store((unsigned*)hp, hu | (up << 16),
                           __ATOMIC_RELAXED, __HIP_MEMORY_SCOPE_AGENT);
      }
      if (t == 63) {
        tail[(size_t)layer*32768 + (size_t)r*1024 + col]         = hn;
        tail[65536 + (size_t)layer*32768 + (size_t)r*1024 + col] = creg;
      }
    }
    if (s == 64) break;                 // no barrier after the last step
    gridbar2(bar, grpid, s, tid);
  }
}

// ---------------------------------------------------------------------------
// Pack Whh0 / Wih1 / Whh1 into per-block MFMA-fragment order (bf16).
// ---------------------------------------------------------------------------
__global__ __launch_bounds__(256)
void k_pack(const float* __restrict__ Whh0, const float* __restrict__ Wih1,
            const float* __restrict__ Whh1, bf16* __restrict__ Wpack)
{
  const int b = blockIdx.x;
  #pragma unroll 4
  for (int it = 0; it < 24; ++it) {
    const int idx = it*256 + threadIdx.x;
    const int chunkp = idx >> 6;            // 0..95
    const int l = idx & 63;
    const int p = chunkp >> 5, c = chunkp & 31;
    const float* W = (p == 0) ? Whh0 : (p == 1 ? Wih1 : Whh1);
    const int j = l & 15;
    const int row = (j>>2)*1024 + b*4 + (j&3);
    const int k = c*32 + (l>>4)*8;
    const float* src = W + (size_t)row*1024 + k;
    bf16* dst = Wpack + ((size_t)(b*96 + chunkp)*64 + l)*8;
    #pragma unroll
    for (int q = 0; q < 8; ++q) dst[q] = __float2bfloat16(src[q]);
  }
}

// ---------------------------------------------------------------------------
// small helpers
// ---------------------------------------------------------------------------
__global__ void k_cvt(const float* __restrict__ s, bf16* __restrict__ d, long n) {
  long i = (long)blockIdx.x*blockDim.x + threadIdx.x;
  if (i < n) d[i] = __float2bfloat16(s[i]);
}

// Wih0 cast with ROW PERMUTATION: dst row n <- src row ((n>>2)&3)*1024 + (n>>4)*4 + (n&3)
__global__ void k_cvt_perm(const float* __restrict__ src, bf16* __restrict__ dst) {
  const int n = blockIdx.x;                 // 0..4095 (permuted row)
  const int orig = ((n>>2)&3)*1024 + (n>>4)*4 + (n&3);
  const float4 v = ((const float4*)(src + (size_t)orig*512))[threadIdx.x];
  bf16* d = dst + (size_t)n*512 + threadIdx.x*4;
  d[0] = __float2bfloat16(v.x); d[1] = __float2bfloat16(v.y);
  d[2] = __float2bfloat16(v.z); d[3] = __float2bfloat16(v.w);
}

__global__ void k_cvt_pad(const float* __restrict__ s, bf16* __restrict__ d,
                          long n, long nrows_real, int rowlen) {
  long i = (long)blockIdx.x*blockDim.x + threadIdx.x;
  if (i < n) {
    long r = i / rowlen;
    d[i] = (r < nrows_real) ? __float2bfloat16(s[i]) : __float2bfloat16(0.f);
  }
}

__global__ void k_init(const float* __restrict__ hx, bf16* __restrict__ hinit,
                       unsigned* __restrict__ bar) {
  int i = blockIdx.x*blockDim.x + threadIdx.x;
  if (i < 256) bar[i] = 0u;
  if (i < 65536) hinit[i] = __float2bfloat16(hx[i]);
}

__global__ void k_embed(const int* __restrict__ ids, const float* __restrict__ emb_w,
                        bf16* __restrict__ out) {
  const int row = blockIdx.x;
  const int tok = ids[row];
  const float4 v = ((const float4*)(emb_w + (size_t)tok*512))[threadIdx.x];
  bf16* d = out + (size_t)row*512 + threadIdx.x*4;
  d[0] = __float2bfloat16(v.x); d[1] = __float2bfloat16(v.y);
  d[2] = __float2bfloat16(v.z); d[3] = __float2bfloat16(v.w);
}

// ---------------------------------------------------------------------------
extern "C" void kernel_launch(void* const* d_in, const int* in_sizes, int n_in,
                              void* d_out, int out_size, void* d_ws, size_t ws_size,
                              hipStream_t stream) {
  const int*   ids  = (const int*)d_in[0];
  const float* hx   = (const float*)d_in[1];
  const float* cx   = (const float*)d_in[2];
  const float* embw = (const float*)d_in[3];
  const float* Wih0 = (const float*)d_in[4];
  const float* Whh0 = (const float*)d_in[5];
  const float* bih0 = (const float*)d_in[6];
  const float* bhh0 = (const float*)d_in[7];
  const float* Wih1 = (const float*)d_in[8];
  const float* Whh1 = (const float*)d_in[9];
  const float* bih1 = (const float*)d_in[10];
  const float* bhh1 = (const float*)d_in[11];
  const float* Wp   = (const float*)d_in[12];
  const float* bp   = (const float*)d_in[13];
  const float* Wd   = (const float*)d_in[14];
  const float* bd   = (const float*)d_in[15];
  float* out = (float*)d_out;

  char* w = (char*)d_ws;
  bf16* Wih0b = (bf16*)w; w += 4096l*512*2;       // permuted rows
  bf16* Wpack = (bf16*)w; w += 256l*96*64*8*2;    // 24 MB packed recurrent weights
  bf16* Wpb   = (bf16*)w; w += 512l*1024*2;
  bf16* Wdb   = (bf16*)w; w += 50048l*512*2;
  bf16* embb  = (bf16*)w; w += 2048l*512*2;
  float* g0p  = (float*)w; w += 2048l*4096*4;     // [b][t][r][q] layout
  bf16* h0a   = (bf16*)w; w += 2048l*1024*2;
  bf16* h1a   = (bf16*)w; w += 2048l*1024*2;
  bf16* hinit = (bf16*)w; w += 2l*32*1024*2;
  bf16* pb    = (bf16*)w; w += 2048l*512*2;
  unsigned* bar = (unsigned*)w; w += 1024;

  k_cvt_perm<<<4096, 128, 0, stream>>>(Wih0, Wih0b);
  k_cvt<<<(512l*1024 + 255)/256, 256, 0, stream>>>(Wp, Wpb, 512l*1024);
  k_cvt_pad<<<(50048l*512 + 255)/256, 256, 0, stream>>>(Wd, Wdb, 50048l*512, 50000, 512);
  k_init<<<256, 256, 0, stream>>>(hx, hinit, bar);
  k_embed<<<2048, 128, 0, stream>>>(ids, embw, embb);
  k_pack<<<256, 256, 0, stream>>>(Whh0, Wih1, Whh1, Wpack);

  // layer-0 input-side GEMM for ALL timesteps -> g0p layout; folds bih0+bhh0
  gemm_bt<2><<<dim3(32, 16), 256, 0, stream>>>(
      embb, Wih0b, bih0, bhh0, g0p, nullptr, 2048, 4096, 512, 4096);

  // persistent pipelined recurrence: one dispatch, 65 super-steps
  float* tail = out + 102400000l;
  k_lstm_persist<<<256, 256, 0, stream>>>(hinit, cx, Wpack, g0p, bih1, bhh1,
                                          h0a, h1a, tail, bar);

  // predictor: Linear + BN(eval) + tanh -> bf16
  gemm_bt<1><<<dim3(4, 16), 256, 0, stream>>>(
      h1a, Wpb, bp, nullptr, nullptr, pb, 2048, 512, 1024, 512);

  // decoder: [2048,512] @ [50048,512]^T (padded), guarded store to 50000
  gemm_bt<0><<<dim3(391, 16), 256, 0, stream>>>(
      pb, Wdb, bd, nullptr, out, nullptr, 2048, 50048, 512, 50000);
}